// Round 8
// baseline (320.779 us; speedup 1.0000x reference)
//
#include <hip/hip_runtime.h>
#include <hip/hip_fp16.h>

#define NNODES   4000
#define TSTEPS   32
#define HDIM     64
#define ECOUNT   1024000
#define NTOT     128000        // NNODES * TSTEPS
#define BATCHB   8
#define NNEUR    500
#define TEBD     16
#define NSTEPS   12

#define CNT_SHIFT 44
#define SUM_MASK  ((1ull << CNT_SHIFT) - 1ull)
#define SLOTS     32           // fixed bucket stride; P(indeg>32) ~ 1e-10 (Poisson mean 8)
#define REC_BLOCKS (NNODES / 32)   // 125 blocks x 32 nodes
#define HIST_BLOCKS (ECOUNT / 512) // 2000 blocks x 512 edges

typedef _Float16 half8_t __attribute__((ext_vector_type(8)));
typedef float    f32x4_t __attribute__((ext_vector_type(4)));

__device__ __forceinline__ float sigmoidf_(float x) {
    return 1.0f / (1.0f + __expf(-x));
}
__device__ __forceinline__ float tanhf_(float x) {
    return 1.0f - 2.0f / (1.0f + __expf(2.0f * x));
}

// ---------------- fused: MFMA GRU recurrence (blocks 0..124, 32 nodes each)
//                  + packed degree/count histogram (blocks 125..2124) ------
// Rec: 8 waves/block = two independent 16-node groups x 4 feature-stripe
// waves -> 2 rec waves/SIMD for latency hiding on the serial 32-step chain.
// Hist: one u64 atomic per edge packs sum(w) fixed-point (low 44 bits) +
// count (high); returned count = edge's rank in its dst bucket -> direct
// scatter se32[d*SLOTS+rank] = {src, w}. No scan, no second pass.
// Fragment layouts (gfx950 16x16x32): A[m=lane&15][k=quad*8+j],
// B[k=quad*8+j][n=lane&15], C[m=quad*4+reg][n=lane&15].
__global__ __launch_bounds__(512) void k_recHist(
    const float* __restrict__ x, const float* __restrict__ Wih,
    const float* __restrict__ Whh, const float* __restrict__ bih,
    const float* __restrict__ bhh, const float* __restrict__ Wg,
    _Float16* __restrict__ xwh,
    const int* __restrict__ ei, const float* __restrict__ ea,
    unsigned long long* __restrict__ dc, int2* __restrict__ se32)
{
    __shared__ __align__(16) _Float16 hbuf[2][32 * 72];   // 2 groups x 16 rows, stride 72

    const int tid = threadIdx.x;

    if (blockIdx.x >= REC_BLOCKS) {
        // -------- histogram path --------
        int e = (blockIdx.x - REC_BLOCKS) * 512 + tid;   // covers exactly ECOUNT
        int s = ei[e], d = ei[ECOUNT + e];
        float w = ea[e];
        unsigned long long fx = (unsigned long long)(w * 4294967296.0f + 0.5f);
        unsigned long long old = atomicAdd(&dc[d], (1ull << CNT_SHIFT) | fx);
        int r = (int)(old >> CNT_SHIFT);
        if (r < SLOTS)   // safety clamp; statistically never taken
            se32[d * SLOTS + r] = make_int2(s, __float_as_int(w));
        return;
    }

    // -------- recurrence path --------
    const int lane = tid & 63;
    const int wv   = tid >> 6;       // 0..7
    const int grp  = wv >> 2;        // node group 0..1
    const int st   = wv & 3;         // feature stripe 0..3
    const int c    = lane & 15;
    const int quad = lane >> 4;
    const int n0   = blockIdx.x * 32 + grp * 16;

    auto makeB = [&](const float* W, int row, int k0) -> half8_t {
        const float4* p = (const float4*)(W + (size_t)row * HDIM + k0);
        float4 u = p[0], v = p[1];
        half8_t h;
        h[0] = (_Float16)u.x; h[1] = (_Float16)u.y; h[2] = (_Float16)u.z; h[3] = (_Float16)u.w;
        h[4] = (_Float16)v.x; h[5] = (_Float16)v.y; h[6] = (_Float16)v.z; h[7] = (_Float16)v.w;
        return h;
    };

    half8_t Bxr[2], Bxz[2], Bxn[2], Bhr[2], Bhz[2], Bhn[2], Bw[2];
#pragma unroll
    for (int kt = 0; kt < 2; ++kt) {
        int k0 = kt * 32 + quad * 8;
        Bxr[kt] = makeB(Wih, st * 16 + c, k0);
        Bxz[kt] = makeB(Wih, 64 + st * 16 + c, k0);
        Bxn[kt] = makeB(Wih, 128 + st * 16 + c, k0);
        Bhr[kt] = makeB(Whh, st * 16 + c, k0);
        Bhz[kt] = makeB(Whh, 64 + st * 16 + c, k0);
        Bhn[kt] = makeB(Whh, 128 + st * 16 + c, k0);
        Bw[kt]  = makeB(Wg, st * 16 + c, k0);
    }

    const int f = st * 16 + c;
    const float brz_r = bih[f] + bhh[f];
    const float brz_z = bih[64 + f] + bhh[64 + f];
    const float bin_  = bih[128 + f];
    const float bhn_  = bhh[128 + f];

    float hreg[4] = {0.f, 0.f, 0.f, 0.f};
    half8_t ah[2];

    const float* xp = x + (size_t)(n0 + c) * (TSTEPS * HDIM) + quad * 8;
    _Float16* hb0 = &hbuf[0][grp * 16 * 72];
    _Float16* hb1 = &hbuf[1][grp * 16 * 72];

    float4 xq0[4], xq1[4];
    {
        const float* p0 = xp;
        xq0[0] = *(const float4*)(p0);      xq0[1] = *(const float4*)(p0 + 4);
        xq0[2] = *(const float4*)(p0 + 32); xq0[3] = *(const float4*)(p0 + 36);
        const float* p1 = xp + HDIM;
        xq1[0] = *(const float4*)(p1);      xq1[1] = *(const float4*)(p1 + 4);
        xq1[2] = *(const float4*)(p1 + 32); xq1[3] = *(const float4*)(p1 + 36);
    }

    auto step = [&](int t, float4* xq, _Float16* hb) {
        half8_t ax[2];
#pragma unroll
        for (int kt = 0; kt < 2; ++kt) {
            float4 u = xq[kt * 2], v = xq[kt * 2 + 1];
            half8_t a;
            a[0] = (_Float16)u.x; a[1] = (_Float16)u.y; a[2] = (_Float16)u.z; a[3] = (_Float16)u.w;
            a[4] = (_Float16)v.x; a[5] = (_Float16)v.y; a[6] = (_Float16)v.z; a[7] = (_Float16)v.w;
            ax[kt] = a;
        }
        if (t + 2 < TSTEPS) {
            const float* pt = xp + (size_t)(t + 2) * HDIM;
            xq[0] = *(const float4*)(pt);      xq[1] = *(const float4*)(pt + 4);
            xq[2] = *(const float4*)(pt + 32); xq[3] = *(const float4*)(pt + 36);
        }

        f32x4_t Cr  = (f32x4_t){0.f, 0.f, 0.f, 0.f};
        f32x4_t Cz  = (f32x4_t){0.f, 0.f, 0.f, 0.f};
        f32x4_t Cnx = (f32x4_t){0.f, 0.f, 0.f, 0.f};
        f32x4_t Cnh = (f32x4_t){0.f, 0.f, 0.f, 0.f};

#pragma unroll
        for (int kt = 0; kt < 2; ++kt) {
            Cr  = __builtin_amdgcn_mfma_f32_16x16x32_f16(ax[kt], Bxr[kt], Cr, 0, 0, 0);
            Cz  = __builtin_amdgcn_mfma_f32_16x16x32_f16(ax[kt], Bxz[kt], Cz, 0, 0, 0);
            Cnx = __builtin_amdgcn_mfma_f32_16x16x32_f16(ax[kt], Bxn[kt], Cnx, 0, 0, 0);
        }
        if (t > 0) {
#pragma unroll
            for (int kt = 0; kt < 2; ++kt) {
                Cr  = __builtin_amdgcn_mfma_f32_16x16x32_f16(ah[kt], Bhr[kt], Cr, 0, 0, 0);
                Cz  = __builtin_amdgcn_mfma_f32_16x16x32_f16(ah[kt], Bhz[kt], Cz, 0, 0, 0);
                Cnh = __builtin_amdgcn_mfma_f32_16x16x32_f16(ah[kt], Bhn[kt], Cnh, 0, 0, 0);
            }
        }

#pragma unroll
        for (int r = 0; r < 4; ++r) {
            float rr = sigmoidf_(Cr[r] + brz_r);
            float zz = sigmoidf_(Cz[r] + brz_z);
            float nn = tanhf_(Cnx[r] + bin_ + rr * (Cnh[r] + bhn_));
            float hn = (1.0f - zz) * nn + zz * hreg[r];
            hreg[r] = hn;
            hb[(quad * 4 + r) * 72 + f] = (_Float16)hn;
        }

        __syncthreads();

#pragma unroll
        for (int kt = 0; kt < 2; ++kt)
            ah[kt] = *(half8_t*)&hb[c * 72 + kt * 32 + quad * 8];

        f32x4_t Cw = (f32x4_t){0.f, 0.f, 0.f, 0.f};
#pragma unroll
        for (int kt = 0; kt < 2; ++kt)
            Cw = __builtin_amdgcn_mfma_f32_16x16x32_f16(ah[kt], Bw[kt], Cw, 0, 0, 0);

#pragma unroll
        for (int r = 0; r < 4; ++r) {
            int row = (n0 + quad * 4 + r) * TSTEPS + t;
            xwh[(size_t)row * HDIM + f] = (_Float16)Cw[r];
        }
    };

#pragma unroll 1
    for (int tt = 0; tt < TSTEPS; tt += 2) {
        step(tt, xq0, hb0);
        step(tt + 1, xq1, hb1);
    }
}

// ---------------- bucket gather: one wave per destination row -------------
// Fixed-stride buckets; dis computed inline from the packed histogram
// (wave-uniform 8 B load + rsqrt, no dis table / no k_dis launch).
// Masked chunks of 8 with 8 independent accumulators: mean indegree 8 ->
// typically ONE fully-pipelined chunk, no serial remainder loop. Masked
// slots clamp src->d, w->0 so poisoned slots are never consumed.
__global__ __launch_bounds__(256) void k_gather(
    const _Float16* __restrict__ xwh, const unsigned long long* __restrict__ dc,
    const int2* __restrict__ se32, _Float16* __restrict__ y)
{
    const int lane = threadIdx.x & 63;
    const int d = blockIdx.x * 4 + (threadIdx.x >> 6);
    const unsigned long long dcd = dc[d];
    int cnt = (int)(dcd >> CNT_SHIFT);
    cnt = cnt < SLOTS ? cnt : SLOTS;
    const float dd = rsqrtf(1.0f + (float)(dcd & SUM_MASK) * 0x1p-32f);
    const int2* bkt = se32 + (size_t)d * SLOTS;

    float acc[8];
    acc[0] = dd * (float)xwh[(size_t)d * HDIM + lane];   // self-loop (x dd at end)
#pragma unroll
    for (int k = 1; k < 8; ++k) acc[k] = 0.f;

#pragma unroll 1
    for (int j = 0; j < cnt; j += 8) {
#pragma unroll
        for (int k = 0; k < 8; ++k) {
            int jj = j + k;
            int2 e = bkt[jj < SLOTS ? jj : SLOTS - 1];
            bool val = jj < cnt;
            int src = val ? e.x : d;
            float w = val ? __int_as_float(e.y) : 0.f;
            unsigned long long dcs = dc[src];
            float ds = rsqrtf(1.0f + (float)(dcs & SUM_MASK) * 0x1p-32f);
            float v = (float)xwh[(size_t)src * HDIM + lane];
            acc[k] = fmaf(ds * w, v, acc[k]);
        }
    }
    float s = ((acc[0] + acc[1]) + (acc[2] + acc[3]))
            + ((acc[4] + acc[5]) + (acc[6] + acc[7]));
    y[(size_t)d * HDIM + lane] = (_Float16)(dd * s);
}

// ---------------- per-(b,t) partial sums over 500 neurons ----------------
__global__ __launch_bounds__(256) void k_S(const _Float16* __restrict__ y,
                                           float* __restrict__ S) {
    const int bt = blockIdx.x;           // 0..255
    const int tid = threadIdx.x;
    const int h = tid & 63, g = tid >> 6;
    const _Float16* base = y + (size_t)bt * (NNEUR * HDIM);
    float acc = 0.f;
    for (int n = g; n < NNEUR; n += 4) acc += (float)base[n * HDIM + h];
    __shared__ float red[256];
    red[tid] = acc;
    __syncthreads();
    if (tid < 64)
        S[bt * 64 + tid] = red[tid] + red[64 + tid] + red[128 + tid] + red[192 + tid];
}

// ---------------- attention MLP + pooling + FC head (one block) ----------------
__global__ __launch_bounds__(256) void k_final(
    const float* __restrict__ S, const float* __restrict__ W1,
    const float* __restrict__ W2, const float* __restrict__ fcW,
    const float* __restrict__ fcb, float* __restrict__ out)
{
    __shared__ float xt[256];
    __shared__ float a1[128];
    __shared__ float attn[256];
    __shared__ float pooled[512];
    const int tid = threadIdx.x;

    {
        float s = 0.f;
        const float* p = S + tid * 64;
#pragma unroll
        for (int hh = 0; hh < 64; ++hh) s += p[hh];
        xt[tid] = s * (1.0f / 32000.0f);
    }
    __syncthreads();
    if (tid < 128) {
        int b = tid >> 4, i = tid & 15;
        float s = 0.f;
#pragma unroll
        for (int t = 0; t < 32; ++t) s += xt[b * 32 + t] * W1[i * 32 + t];
        a1[tid] = fmaxf(s, 0.f);
    }
    __syncthreads();
    {
        int b = tid >> 5, t = tid & 31;
        float s = 0.f;
#pragma unroll
        for (int i = 0; i < 16; ++i) s += a1[b * 16 + i] * W2[t * 16 + i];
        attn[tid] = 1.0f / (1.0f + __expf(-s));
    }
    __syncthreads();
    for (int o = tid; o < 512; o += 256) {
        int b = o >> 6, h = o & 63;
        float s = 0.f;
#pragma unroll
        for (int t = 0; t < 32; ++t) s += attn[b * 32 + t] * S[(b * 32 + t) * 64 + h];
        pooled[o] = s;
    }
    __syncthreads();
    if (tid < BATCHB * NSTEPS) {
        int b = tid / NSTEPS, st = tid % NSTEPS;
        float acc = fcb[st];
#pragma unroll
        for (int h = 0; h < 64; ++h) acc += pooled[b * 64 + h] * fcW[st * 64 + h];
        out[b * NSTEPS + st] = acc;
    }
}

extern "C" void kernel_launch(void* const* d_in, const int* in_sizes, int n_in,
                              void* d_out, int out_size, void* d_ws, size_t ws_size,
                              hipStream_t stream) {
    const float* x   = (const float*)d_in[0];
    const int*   ei  = (const int*)  d_in[1];
    const float* ea  = (const float*)d_in[2];
    // d_in[3] = batch: unused by the reference computation
    const float* Wih = (const float*)d_in[4];
    const float* Whh = (const float*)d_in[5];
    const float* bih = (const float*)d_in[6];
    const float* bhh = (const float*)d_in[7];
    const float* Wg  = (const float*)d_in[8];
    const float* W1  = (const float*)d_in[9];
    const float* W2  = (const float*)d_in[10];
    const float* fcW = (const float*)d_in[11];
    const float* fcb = (const float*)d_in[12];
    float* out = (float*)d_out;

    // workspace layout (~66.6 MB), 8-byte-aligned chunks first
    char* p = (char*)d_ws;
    unsigned long long* dc = (unsigned long long*)p; p += sizeof(unsigned long long) * NTOT;   // 1.02 MB
    int2*  se32 = (int2*)p;        p += sizeof(int2) * (size_t)NTOT * SLOTS;                   // 32.77 MB
    _Float16* xwh = (_Float16*)p;  p += sizeof(_Float16) * (size_t)NTOT * HDIM;                // 16.38 MB
    _Float16* y   = (_Float16*)p;  p += sizeof(_Float16) * (size_t)NTOT * HDIM;                // 16.38 MB
    float* S   = (float*)p;                                                                    // 64 KB

    hipMemsetAsync(dc, 0, sizeof(unsigned long long) * NTOT, stream);
    k_recHist <<<REC_BLOCKS + HIST_BLOCKS, 512, 0, stream>>>(
        x, Wih, Whh, bih, bhh, Wg, xwh, ei, ea, dc, se32);
    k_gather  <<<NTOT / 4, 256, 0, stream>>>(xwh, dc, se32, y);
    k_S       <<<256, 256, 0, stream>>>(y, S);
    k_final   <<<1, 256, 0, stream>>>(S, W1, W2, fcW, fcb, out);
}

// Round 9
// 301.247 us; speedup vs baseline: 1.0648x; 1.0648x over previous
//
#include <hip/hip_runtime.h>
#include <hip/hip_fp16.h>

#define NNODES   4000
#define TSTEPS   32
#define HDIM     64
#define ECOUNT   1024000
#define NTOT     128000        // NNODES * TSTEPS
#define XELEMS   (NNODES * TSTEPS * HDIM)   // 8.192M
#define BATCHB   8
#define NNEUR    500
#define TEBD     16
#define NSTEPS   12

#define CNT_SHIFT 44
#define SUM_MASK  ((1ull << CNT_SHIFT) - 1ull)
#define SLOTS     32           // fixed bucket stride; P(indeg>32) ~ 1e-10 (Poisson mean 8)
#define REC_BLOCKS (NNODES / 16)     // 250 rec blocks x 16 nodes (4 waves)
#define HIST_BLOCKS (ECOUNT / 256)   // 4000 hist blocks x 256 edges

typedef _Float16 half8_t __attribute__((ext_vector_type(8)));
typedef float    f32x4_t __attribute__((ext_vector_type(4)));

__device__ __forceinline__ float sigmoidf_(float x) {
    return 1.0f / (1.0f + __expf(-x));
}
__device__ __forceinline__ float tanhf_(float x) {
    return 1.0f - 2.0f / (1.0f + __expf(2.0f * x));
}

// ---------------- prep: zero dc histogram + convert x fp32 -> fp16 --------
// Replaces the hipMemsetAsync launch. fp16 x halves recHist's redundant
// x streaming (4 stripe-waves re-read the same tile) and deletes the
// per-step cvt+pack VALU from the serial GRU chain.
__global__ __launch_bounds__(256) void k_prep(const float* __restrict__ x,
                                              _Float16* __restrict__ xh,
                                              unsigned long long* __restrict__ dc) {
    int g = blockIdx.x * blockDim.x + threadIdx.x;
    if (g < NTOT) dc[g] = 0ull;
    int i = g * 8;
    if (i < XELEMS) {
        const float4* p = (const float4*)(x + i);
        float4 u = p[0], v = p[1];
        half8_t h;
        h[0] = (_Float16)u.x; h[1] = (_Float16)u.y; h[2] = (_Float16)u.z; h[3] = (_Float16)u.w;
        h[4] = (_Float16)v.x; h[5] = (_Float16)v.y; h[6] = (_Float16)v.z; h[7] = (_Float16)v.w;
        *(half8_t*)(xh + i) = h;
    }
}

// ---------------- fused: MFMA GRU recurrence (blocks 0..249, 16 nodes) +
//                  packed degree/count histogram (blocks 250..4249) --------
// Hist: one u64 atomic per edge packs sum(w) fixed-point (low 44 bits,
// 2^-32 resolution) + count (high bits); returned count = edge's rank in
// its dst bucket -> direct scatter se32[d*SLOTS+rank] = {src, w}.
// Rec: one block (4 waves) owns 16 nodes for all 32 timesteps; wave wv owns
// the 16-feature stripe of each gate. Weight B-frags in VGPRs; LDS only a
// 2x(16x72) fp16 ping-pong for the C->A h transpose; 1 barrier/step.
// x read directly as fp16 A-frags (16 B/lane per K-tile), prefetch dist 2.
// Fragment layouts (gfx950 16x16x32): A[m=lane&15][k=quad*8+j],
// B[k=quad*8+j][n=lane&15], C[m=quad*4+reg][n=lane&15].
__global__ __launch_bounds__(256) void k_recHist(
    const _Float16* __restrict__ xh, const float* __restrict__ Wih,
    const float* __restrict__ Whh, const float* __restrict__ bih,
    const float* __restrict__ bhh, const float* __restrict__ Wg,
    _Float16* __restrict__ xwh,
    const int* __restrict__ ei, const float* __restrict__ ea,
    unsigned long long* __restrict__ dc, int2* __restrict__ se32)
{
    __shared__ __align__(16) _Float16 hbuf[2][16 * 72];   // stride 72: conflict-free

    const int tid = threadIdx.x;

    if (blockIdx.x >= REC_BLOCKS) {
        // -------- histogram path --------
        int e = (blockIdx.x - REC_BLOCKS) * 256 + tid;   // covers exactly ECOUNT
        int s = ei[e], d = ei[ECOUNT + e];
        float w = ea[e];
        unsigned long long fx = (unsigned long long)(w * 4294967296.0f + 0.5f);
        unsigned long long old = atomicAdd(&dc[d], (1ull << CNT_SHIFT) | fx);
        int r = (int)(old >> CNT_SHIFT);
        if (r < SLOTS)   // safety clamp; statistically never taken
            se32[d * SLOTS + r] = make_int2(s, __float_as_int(w));
        return;
    }

    // -------- recurrence path --------
    const int lane = tid & 63;
    const int wv   = tid >> 6;       // feature stripe 0..3
    const int c    = lane & 15;
    const int quad = lane >> 4;
    const int n0   = blockIdx.x * 16;

    auto makeB = [&](const float* W, int row, int k0) -> half8_t {
        const float4* p = (const float4*)(W + (size_t)row * HDIM + k0);
        float4 u = p[0], v = p[1];
        half8_t h;
        h[0] = (_Float16)u.x; h[1] = (_Float16)u.y; h[2] = (_Float16)u.z; h[3] = (_Float16)u.w;
        h[4] = (_Float16)v.x; h[5] = (_Float16)v.y; h[6] = (_Float16)v.z; h[7] = (_Float16)v.w;
        return h;
    };

    half8_t Bxr[2], Bxz[2], Bxn[2], Bhr[2], Bhz[2], Bhn[2], Bw[2];
#pragma unroll
    for (int kt = 0; kt < 2; ++kt) {
        int k0 = kt * 32 + quad * 8;
        Bxr[kt] = makeB(Wih, wv * 16 + c, k0);
        Bxz[kt] = makeB(Wih, 64 + wv * 16 + c, k0);
        Bxn[kt] = makeB(Wih, 128 + wv * 16 + c, k0);
        Bhr[kt] = makeB(Whh, wv * 16 + c, k0);
        Bhz[kt] = makeB(Whh, 64 + wv * 16 + c, k0);
        Bhn[kt] = makeB(Whh, 128 + wv * 16 + c, k0);
        Bw[kt]  = makeB(Wg, wv * 16 + c, k0);
    }

    const int f = wv * 16 + c;
    const float brz_r = bih[f] + bhh[f];
    const float brz_z = bih[64 + f] + bhh[64 + f];
    const float bin_  = bih[128 + f];
    const float bhn_  = bhh[128 + f];

    float hreg[4] = {0.f, 0.f, 0.f, 0.f};
    half8_t ah[2];

    const _Float16* xp = xh + (size_t)(n0 + c) * (TSTEPS * HDIM) + quad * 8;

    half8_t xq0[2], xq1[2];
#pragma unroll
    for (int kt = 0; kt < 2; ++kt) {
        xq0[kt] = *(const half8_t*)(xp + kt * 32);
        xq1[kt] = *(const half8_t*)(xp + HDIM + kt * 32);
    }

    auto step = [&](int t, half8_t* xq) {
        half8_t ax[2];
#pragma unroll
        for (int kt = 0; kt < 2; ++kt) ax[kt] = xq[kt];
        if (t + 2 < TSTEPS) {
            const _Float16* pt = xp + (size_t)(t + 2) * HDIM;
#pragma unroll
            for (int kt = 0; kt < 2; ++kt)
                xq[kt] = *(const half8_t*)(pt + kt * 32);
        }

        f32x4_t Cr  = (f32x4_t){0.f, 0.f, 0.f, 0.f};
        f32x4_t Cz  = (f32x4_t){0.f, 0.f, 0.f, 0.f};
        f32x4_t Cnx = (f32x4_t){0.f, 0.f, 0.f, 0.f};
        f32x4_t Cnh = (f32x4_t){0.f, 0.f, 0.f, 0.f};

#pragma unroll
        for (int kt = 0; kt < 2; ++kt) {
            Cr  = __builtin_amdgcn_mfma_f32_16x16x32_f16(ax[kt], Bxr[kt], Cr, 0, 0, 0);
            Cz  = __builtin_amdgcn_mfma_f32_16x16x32_f16(ax[kt], Bxz[kt], Cz, 0, 0, 0);
            Cnx = __builtin_amdgcn_mfma_f32_16x16x32_f16(ax[kt], Bxn[kt], Cnx, 0, 0, 0);
        }
        if (t > 0) {
#pragma unroll
            for (int kt = 0; kt < 2; ++kt) {
                Cr  = __builtin_amdgcn_mfma_f32_16x16x32_f16(ah[kt], Bhr[kt], Cr, 0, 0, 0);
                Cz  = __builtin_amdgcn_mfma_f32_16x16x32_f16(ah[kt], Bhz[kt], Cz, 0, 0, 0);
                Cnh = __builtin_amdgcn_mfma_f32_16x16x32_f16(ah[kt], Bhn[kt], Cnh, 0, 0, 0);
            }
        }

        _Float16* hb = hbuf[t & 1];
#pragma unroll
        for (int r = 0; r < 4; ++r) {
            float rr = sigmoidf_(Cr[r] + brz_r);
            float zz = sigmoidf_(Cz[r] + brz_z);
            float nn = tanhf_(Cnx[r] + bin_ + rr * (Cnh[r] + bhn_));
            float hn = (1.0f - zz) * nn + zz * hreg[r];
            hreg[r] = hn;
            hb[(quad * 4 + r) * 72 + f] = (_Float16)hn;
        }

        __syncthreads();

#pragma unroll
        for (int kt = 0; kt < 2; ++kt)
            ah[kt] = *(half8_t*)&hb[c * 72 + kt * 32 + quad * 8];

        f32x4_t Cw = (f32x4_t){0.f, 0.f, 0.f, 0.f};
#pragma unroll
        for (int kt = 0; kt < 2; ++kt)
            Cw = __builtin_amdgcn_mfma_f32_16x16x32_f16(ah[kt], Bw[kt], Cw, 0, 0, 0);

#pragma unroll
        for (int r = 0; r < 4; ++r) {
            int row = (n0 + quad * 4 + r) * TSTEPS + t;
            xwh[(size_t)row * HDIM + f] = (_Float16)Cw[r];
        }
    };

#pragma unroll 1
    for (int tt = 0; tt < TSTEPS; tt += 2) {
        step(tt, xq0);
        step(tt + 1, xq1);
    }
}

// ---------------- dis = rsqrt(1 + sum(w)) from packed histogram ----------
__global__ void k_dis(const unsigned long long* __restrict__ dc,
                      float* __restrict__ dis) {
    int i = blockIdx.x * blockDim.x + threadIdx.x;
    if (i < NTOT) {
        float deg = 1.0f + (float)(dc[i] & SUM_MASK) * 0x1p-32f;  // +1 self-loop
        dis[i] = rsqrtf(deg);
    }
}

// ---------------- bucket gather: one wave per destination row -------------
// Fixed-stride buckets, coef = dis[src]*w from the precomputed dis TABLE
// (4 B cached load + 1 mul per edge — the R7 inline-u64 version doubled
// VALU and regressed 2x). 8-wide masked unroll, 8 independent accumulators:
// mean indegree 8 -> typically one fully-pipelined chunk, no serial
// remainder. Masked slots clamp src->d, w->0.
__global__ __launch_bounds__(256) void k_gather(
    const _Float16* __restrict__ xwh, const unsigned long long* __restrict__ dc,
    const int2* __restrict__ se32, const float* __restrict__ dis,
    _Float16* __restrict__ y)
{
    const int lane = threadIdx.x & 63;
    const int d = blockIdx.x * 4 + (threadIdx.x >> 6);
    const float dd = dis[d];
    int cnt = (int)(dc[d] >> CNT_SHIFT);
    cnt = cnt < SLOTS ? cnt : SLOTS;
    const int2* bkt = se32 + (size_t)d * SLOTS;

    float acc[8];
    acc[0] = dd * (float)xwh[(size_t)d * HDIM + lane];   // self-loop (x dd at end)
#pragma unroll
    for (int k = 1; k < 8; ++k) acc[k] = 0.f;

#pragma unroll 1
    for (int j = 0; j < cnt; j += 8) {
#pragma unroll
        for (int k = 0; k < 8; ++k) {
            int jj = j + k;
            int2 e = bkt[jj < SLOTS ? jj : SLOTS - 1];
            bool val = jj < cnt;
            int src = val ? e.x : d;
            float w = val ? __int_as_float(e.y) : 0.f;
            float cf = dis[src] * w;
            float v = (float)xwh[(size_t)src * HDIM + lane];
            acc[k] = fmaf(cf, v, acc[k]);
        }
    }
    float s = ((acc[0] + acc[1]) + (acc[2] + acc[3]))
            + ((acc[4] + acc[5]) + (acc[6] + acc[7]));
    y[(size_t)d * HDIM + lane] = (_Float16)(dd * s);
}

// ---------------- per-(b,t) partial sums over 500 neurons ----------------
__global__ __launch_bounds__(256) void k_S(const _Float16* __restrict__ y,
                                           float* __restrict__ S) {
    const int bt = blockIdx.x;           // 0..255
    const int tid = threadIdx.x;
    const int h = tid & 63, g = tid >> 6;
    const _Float16* base = y + (size_t)bt * (NNEUR * HDIM);
    float acc = 0.f;
    for (int n = g; n < NNEUR; n += 4) acc += (float)base[n * HDIM + h];
    __shared__ float red[256];
    red[tid] = acc;
    __syncthreads();
    if (tid < 64)
        S[bt * 64 + tid] = red[tid] + red[64 + tid] + red[128 + tid] + red[192 + tid];
}

// ---------------- attention MLP + pooling + FC head (one block) ----------------
__global__ __launch_bounds__(256) void k_final(
    const float* __restrict__ S, const float* __restrict__ W1,
    const float* __restrict__ W2, const float* __restrict__ fcW,
    const float* __restrict__ fcb, float* __restrict__ out)
{
    __shared__ float xt[256];
    __shared__ float a1[128];
    __shared__ float attn[256];
    __shared__ float pooled[512];
    const int tid = threadIdx.x;

    {
        float s = 0.f;
        const float* p = S + tid * 64;
#pragma unroll
        for (int hh = 0; hh < 64; ++hh) s += p[hh];
        xt[tid] = s * (1.0f / 32000.0f);
    }
    __syncthreads();
    if (tid < 128) {
        int b = tid >> 4, i = tid & 15;
        float s = 0.f;
#pragma unroll
        for (int t = 0; t < 32; ++t) s += xt[b * 32 + t] * W1[i * 32 + t];
        a1[tid] = fmaxf(s, 0.f);
    }
    __syncthreads();
    {
        int b = tid >> 5, t = tid & 31;
        float s = 0.f;
#pragma unroll
        for (int i = 0; i < 16; ++i) s += a1[b * 16 + i] * W2[t * 16 + i];
        attn[tid] = 1.0f / (1.0f + __expf(-s));
    }
    __syncthreads();
    for (int o = tid; o < 512; o += 256) {
        int b = o >> 6, h = o & 63;
        float s = 0.f;
#pragma unroll
        for (int t = 0; t < 32; ++t) s += attn[b * 32 + t] * S[(b * 32 + t) * 64 + h];
        pooled[o] = s;
    }
    __syncthreads();
    if (tid < BATCHB * NSTEPS) {
        int b = tid / NSTEPS, st = tid % NSTEPS;
        float acc = fcb[st];
#pragma unroll
        for (int h = 0; h < 64; ++h) acc += pooled[b * 64 + h] * fcW[st * 64 + h];
        out[b * NSTEPS + st] = acc;
    }
}

extern "C" void kernel_launch(void* const* d_in, const int* in_sizes, int n_in,
                              void* d_out, int out_size, void* d_ws, size_t ws_size,
                              hipStream_t stream) {
    const float* x   = (const float*)d_in[0];
    const int*   ei  = (const int*)  d_in[1];
    const float* ea  = (const float*)d_in[2];
    // d_in[3] = batch: unused by the reference computation
    const float* Wih = (const float*)d_in[4];
    const float* Whh = (const float*)d_in[5];
    const float* bih = (const float*)d_in[6];
    const float* bhh = (const float*)d_in[7];
    const float* Wg  = (const float*)d_in[8];
    const float* W1  = (const float*)d_in[9];
    const float* W2  = (const float*)d_in[10];
    const float* fcW = (const float*)d_in[11];
    const float* fcb = (const float*)d_in[12];
    float* out = (float*)d_out;

    // workspace layout (~67.1 MB); y aliases xh (dead after k_recHist)
    char* p = (char*)d_ws;
    unsigned long long* dc = (unsigned long long*)p; p += sizeof(unsigned long long) * NTOT;   // 1.02 MB
    int2*  se32 = (int2*)p;        p += sizeof(int2) * (size_t)NTOT * SLOTS;                   // 32.77 MB
    _Float16* xh  = (_Float16*)p;  p += sizeof(_Float16) * (size_t)XELEMS;                     // 16.38 MB
    _Float16* xwh = (_Float16*)p;  p += sizeof(_Float16) * (size_t)NTOT * HDIM;                // 16.38 MB
    float* dis = (float*)p;        p += sizeof(float) * NTOT;                                  // 0.51 MB
    float* S   = (float*)p;                                                                    // 64 KB
    _Float16* y = xh;   // reuse: xh is consumed only by k_recHist

    k_prep    <<<(XELEMS / 8 + 255) / 256, 256, 0, stream>>>(x, xh, dc);
    k_recHist <<<REC_BLOCKS + HIST_BLOCKS, 256, 0, stream>>>(
        xh, Wih, Whh, bih, bhh, Wg, xwh, ei, ea, dc, se32);
    k_dis     <<<(NTOT + 255) / 256, 256, 0, stream>>>(dc, dis);
    k_gather  <<<NTOT / 4, 256, 0, stream>>>(xwh, dc, se32, dis, y);
    k_S       <<<256, 256, 0, stream>>>(y, S);
    k_final   <<<1, 256, 0, stream>>>(S, W1, W2, fcW, fcb, out);
}

// Round 10
// 288.115 us; speedup vs baseline: 1.1134x; 1.0456x over previous
//
#include <hip/hip_runtime.h>
#include <hip/hip_fp16.h>

#define NNODES   4000
#define TSTEPS   32
#define HDIM     64
#define ECOUNT   1024000
#define NTOT     128000        // NNODES * TSTEPS
#define XELEMS   (NNODES * TSTEPS * HDIM)   // 8.192M
#define BATCHB   8
#define NNEUR    500
#define TEBD     16
#define NSTEPS   12

#define CNT_SHIFT 44
#define SUM_MASK  ((1ull << CNT_SHIFT) - 1ull)
#define REC_BLOCKS (NNODES / 16)     // 250 rec blocks x 16 nodes (4 waves)
#define HIST_BLOCKS (ECOUNT / 256)   // 4000 hist blocks x 256 edges

typedef _Float16 half8_t __attribute__((ext_vector_type(8)));
typedef float    f32x4_t __attribute__((ext_vector_type(4)));

__device__ __forceinline__ float sigmoidf_(float x) {
    return 1.0f / (1.0f + __expf(-x));
}
__device__ __forceinline__ float tanhf_(float x) {
    return 1.0f - 2.0f / (1.0f + __expf(2.0f * x));
}

// ---------------- prep: zero dc histogram + convert x fp32 -> fp16 --------
__global__ __launch_bounds__(256) void k_prep(const float* __restrict__ x,
                                              _Float16* __restrict__ xh,
                                              unsigned long long* __restrict__ dc) {
    int g = blockIdx.x * blockDim.x + threadIdx.x;
    if (g < NTOT) dc[g] = 0ull;
    int i = g * 8;
    if (i < XELEMS) {
        const float4* p = (const float4*)(x + i);
        float4 u = p[0], v = p[1];
        half8_t h;
        h[0] = (_Float16)u.x; h[1] = (_Float16)u.y; h[2] = (_Float16)u.z; h[3] = (_Float16)u.w;
        h[4] = (_Float16)v.x; h[5] = (_Float16)v.y; h[6] = (_Float16)v.z; h[7] = (_Float16)v.w;
        *(half8_t*)(xh + i) = h;
    }
}

// ---------------- fused: MFMA GRU recurrence (blocks 0..249, 16 nodes) +
//                  packed degree/count histogram (blocks 250..4249) --------
// Hist: ONE u64 atomic per edge packs sum(w) fixed-point (low 44 bits,
// 2^-32 resolution) + count (high bits); the returned count is the edge's
// rank within its dst bucket -> stored as u16 for the no-atomic CSR
// scatter in k_esc. (Dense CSR beats fixed-stride buckets in gather: 8
// edges/64B-line on the wave-uniform se reads vs 1, and coef pre-baked.)
// Rec: one block (4 waves) owns 16 nodes for all 32 timesteps; wave wv owns
// the 16-feature stripe of each gate. Weight B-frags in VGPRs; LDS only a
// 2x(16x72) fp16 ping-pong for the C->A h transpose; 1 barrier/step.
// x read directly as fp16 A-frags, prefetch distance 2.
// Fragment layouts (gfx950 16x16x32): A[m=lane&15][k=quad*8+j],
// B[k=quad*8+j][n=lane&15], C[m=quad*4+reg][n=lane&15].
__global__ __launch_bounds__(256) void k_recHist(
    const _Float16* __restrict__ xh, const float* __restrict__ Wih,
    const float* __restrict__ Whh, const float* __restrict__ bih,
    const float* __restrict__ bhh, const float* __restrict__ Wg,
    _Float16* __restrict__ xwh,
    const int* __restrict__ ei, const float* __restrict__ ea,
    unsigned long long* __restrict__ dc, unsigned short* __restrict__ rank)
{
    __shared__ __align__(16) _Float16 hbuf[2][16 * 72];   // stride 72: conflict-free

    const int tid = threadIdx.x;

    if (blockIdx.x >= REC_BLOCKS) {
        // -------- histogram path --------
        int e = (blockIdx.x - REC_BLOCKS) * 256 + tid;   // covers exactly ECOUNT
        int d = ei[ECOUNT + e];
        float w = ea[e];
        unsigned long long fx = (unsigned long long)(w * 4294967296.0f + 0.5f);
        unsigned long long old = atomicAdd(&dc[d], (1ull << CNT_SHIFT) | fx);
        rank[e] = (unsigned short)(old >> CNT_SHIFT);
        return;
    }

    // -------- recurrence path --------
    const int lane = tid & 63;
    const int wv   = tid >> 6;       // feature stripe 0..3
    const int c    = lane & 15;
    const int quad = lane >> 4;
    const int n0   = blockIdx.x * 16;

    auto makeB = [&](const float* W, int row, int k0) -> half8_t {
        const float4* p = (const float4*)(W + (size_t)row * HDIM + k0);
        float4 u = p[0], v = p[1];
        half8_t h;
        h[0] = (_Float16)u.x; h[1] = (_Float16)u.y; h[2] = (_Float16)u.z; h[3] = (_Float16)u.w;
        h[4] = (_Float16)v.x; h[5] = (_Float16)v.y; h[6] = (_Float16)v.z; h[7] = (_Float16)v.w;
        return h;
    };

    half8_t Bxr[2], Bxz[2], Bxn[2], Bhr[2], Bhz[2], Bhn[2], Bw[2];
#pragma unroll
    for (int kt = 0; kt < 2; ++kt) {
        int k0 = kt * 32 + quad * 8;
        Bxr[kt] = makeB(Wih, wv * 16 + c, k0);
        Bxz[kt] = makeB(Wih, 64 + wv * 16 + c, k0);
        Bxn[kt] = makeB(Wih, 128 + wv * 16 + c, k0);
        Bhr[kt] = makeB(Whh, wv * 16 + c, k0);
        Bhz[kt] = makeB(Whh, 64 + wv * 16 + c, k0);
        Bhn[kt] = makeB(Whh, 128 + wv * 16 + c, k0);
        Bw[kt]  = makeB(Wg, wv * 16 + c, k0);
    }

    const int f = wv * 16 + c;
    const float brz_r = bih[f] + bhh[f];
    const float brz_z = bih[64 + f] + bhh[64 + f];
    const float bin_  = bih[128 + f];
    const float bhn_  = bhh[128 + f];

    float hreg[4] = {0.f, 0.f, 0.f, 0.f};
    half8_t ah[2];

    const _Float16* xp = xh + (size_t)(n0 + c) * (TSTEPS * HDIM) + quad * 8;

    half8_t xq0[2], xq1[2];
#pragma unroll
    for (int kt = 0; kt < 2; ++kt) {
        xq0[kt] = *(const half8_t*)(xp + kt * 32);
        xq1[kt] = *(const half8_t*)(xp + HDIM + kt * 32);
    }

    auto step = [&](int t, half8_t* xq) {
        half8_t ax[2];
#pragma unroll
        for (int kt = 0; kt < 2; ++kt) ax[kt] = xq[kt];
        if (t + 2 < TSTEPS) {
            const _Float16* pt = xp + (size_t)(t + 2) * HDIM;
#pragma unroll
            for (int kt = 0; kt < 2; ++kt)
                xq[kt] = *(const half8_t*)(pt + kt * 32);
        }

        f32x4_t Cr  = (f32x4_t){0.f, 0.f, 0.f, 0.f};
        f32x4_t Cz  = (f32x4_t){0.f, 0.f, 0.f, 0.f};
        f32x4_t Cnx = (f32x4_t){0.f, 0.f, 0.f, 0.f};
        f32x4_t Cnh = (f32x4_t){0.f, 0.f, 0.f, 0.f};

#pragma unroll
        for (int kt = 0; kt < 2; ++kt) {
            Cr  = __builtin_amdgcn_mfma_f32_16x16x32_f16(ax[kt], Bxr[kt], Cr, 0, 0, 0);
            Cz  = __builtin_amdgcn_mfma_f32_16x16x32_f16(ax[kt], Bxz[kt], Cz, 0, 0, 0);
            Cnx = __builtin_amdgcn_mfma_f32_16x16x32_f16(ax[kt], Bxn[kt], Cnx, 0, 0, 0);
        }
        if (t > 0) {
#pragma unroll
            for (int kt = 0; kt < 2; ++kt) {
                Cr  = __builtin_amdgcn_mfma_f32_16x16x32_f16(ah[kt], Bhr[kt], Cr, 0, 0, 0);
                Cz  = __builtin_amdgcn_mfma_f32_16x16x32_f16(ah[kt], Bhz[kt], Cz, 0, 0, 0);
                Cnh = __builtin_amdgcn_mfma_f32_16x16x32_f16(ah[kt], Bhn[kt], Cnh, 0, 0, 0);
            }
        }

        _Float16* hb = hbuf[t & 1];
#pragma unroll
        for (int r = 0; r < 4; ++r) {
            float rr = sigmoidf_(Cr[r] + brz_r);
            float zz = sigmoidf_(Cz[r] + brz_z);
            float nn = tanhf_(Cnx[r] + bin_ + rr * (Cnh[r] + bhn_));
            float hn = (1.0f - zz) * nn + zz * hreg[r];
            hreg[r] = hn;
            hb[(quad * 4 + r) * 72 + f] = (_Float16)hn;
        }

        __syncthreads();

#pragma unroll
        for (int kt = 0; kt < 2; ++kt)
            ah[kt] = *(half8_t*)&hb[c * 72 + kt * 32 + quad * 8];

        f32x4_t Cw = (f32x4_t){0.f, 0.f, 0.f, 0.f};
#pragma unroll
        for (int kt = 0; kt < 2; ++kt)
            Cw = __builtin_amdgcn_mfma_f32_16x16x32_f16(ah[kt], Bw[kt], Cw, 0, 0, 0);

#pragma unroll
        for (int r = 0; r < 4; ++r) {
            int row = (n0 + quad * 4 + r) * TSTEPS + t;
            xwh[(size_t)row * HDIM + f] = (_Float16)Cw[r];
        }
    };

#pragma unroll 1
    for (int tt = 0; tt < TSTEPS; tt += 2) {
        step(tt, xq0);
        step(tt + 1, xq1);
    }
}

// ---------------- dis = rsqrt(1 + sum(w)) from packed histogram ----------
__global__ void k_dis(const unsigned long long* __restrict__ dc,
                      float* __restrict__ dis) {
    int i = blockIdx.x * blockDim.x + threadIdx.x;
    if (i < NTOT) {
        float deg = 1.0f + (float)(dc[i] & SUM_MASK) * 0x1p-32f;  // +1 self-loop
        dis[i] = rsqrtf(deg);
    }
}

// ---------------- exclusive scan of counts -> off (3 kernels) -------------
__global__ __launch_bounds__(256) void k_scan1(const unsigned long long* __restrict__ dc,
                                               int* __restrict__ bsum) {
    __shared__ int s[256];
    const int tid = threadIdx.x;
    s[tid] = (int)(dc[blockIdx.x * 256 + tid] >> CNT_SHIFT);
    __syncthreads();
    for (int st = 128; st > 0; st >>= 1) {
        if (tid < st) s[tid] += s[tid + st];
        __syncthreads();
    }
    if (tid == 0) bsum[blockIdx.x] = s[0];
}

__global__ __launch_bounds__(512) void k_scan2(const int* __restrict__ bsum,
                                               int* __restrict__ boff) {
    __shared__ int s[512];
    const int tid = threadIdx.x;
    int v = (tid < NTOT / 256) ? bsum[tid] : 0;
    s[tid] = v;
    __syncthreads();
    for (int st = 1; st < 512; st <<= 1) {
        int a = (tid >= st) ? s[tid - st] : 0;
        __syncthreads();
        s[tid] += a;
        __syncthreads();
    }
    if (tid < NTOT / 256) boff[tid] = s[tid] - v;   // exclusive
}

__global__ __launch_bounds__(256) void k_scan3(const unsigned long long* __restrict__ dc,
                                               const int* __restrict__ boff,
                                               int* __restrict__ off) {
    __shared__ int s[256];
    const int tid = threadIdx.x;
    const int i = blockIdx.x * 256 + tid;
    int v = (int)(dc[i] >> CNT_SHIFT);
    s[tid] = v;
    __syncthreads();
    for (int st = 1; st < 256; st <<= 1) {
        int a = (tid >= st) ? s[tid - st] : 0;
        __syncthreads();
        s[tid] += a;
        __syncthreads();
    }
    off[i] = s[tid] - v + boff[blockIdx.x];
    if (i == 0) off[NTOT] = ECOUNT;
}

// ---------------- CSR scatter (no atomics): pos = off[d] + rank[e] --------
// coef = dis[s]*w*dis[d] pre-baked so gather does one fmaf per edge.
__global__ void k_esc(const int* __restrict__ ei, const float* __restrict__ ea,
                      const float* __restrict__ dis, const int* __restrict__ off,
                      const unsigned short* __restrict__ rank,
                      int2* __restrict__ se) {
    int e = blockIdx.x * blockDim.x + threadIdx.x;
    if (e < ECOUNT) {
        int s = ei[e], d = ei[ECOUNT + e];
        int pos = off[d] + (int)rank[e];
        float cf = dis[s] * ea[e] * dis[d];
        se[pos] = make_int2(s, __float_as_int(cf));
    }
}

// ---------------- CSR gather: one wave per destination row ----------------
// Dense se (8 edges per 64B line on wave-uniform reads), coef pre-baked,
// 4-way unroll + 4 independent accumulators. xwh fp16: 128 B/row gathers.
__global__ __launch_bounds__(256) void k_gather(
    const _Float16* __restrict__ xwh, const int* __restrict__ off,
    const int2* __restrict__ se, const float* __restrict__ dis,
    _Float16* __restrict__ y)
{
    const int lane = threadIdx.x & 63;
    const int d = blockIdx.x * 4 + (threadIdx.x >> 6);
    float dd = dis[d];
    float a0 = dd * dd * (float)xwh[(size_t)d * HDIM + lane];   // self-loop
    float a1 = 0.f, a2 = 0.f, a3 = 0.f;
    const int j0 = off[d], j1 = off[d + 1];
    int j = j0;
    for (; j + 4 <= j1; j += 4) {
        int2 e0 = se[j], e1 = se[j + 1], e2 = se[j + 2], e3 = se[j + 3];
        float v0 = (float)xwh[(size_t)e0.x * HDIM + lane];
        float v1 = (float)xwh[(size_t)e1.x * HDIM + lane];
        float v2 = (float)xwh[(size_t)e2.x * HDIM + lane];
        float v3 = (float)xwh[(size_t)e3.x * HDIM + lane];
        a0 = fmaf(__int_as_float(e0.y), v0, a0);
        a1 = fmaf(__int_as_float(e1.y), v1, a1);
        a2 = fmaf(__int_as_float(e2.y), v2, a2);
        a3 = fmaf(__int_as_float(e3.y), v3, a3);
    }
    for (; j < j1; ++j) {
        int2 e = se[j];
        a0 = fmaf(__int_as_float(e.y), (float)xwh[(size_t)e.x * HDIM + lane], a0);
    }
    y[(size_t)d * HDIM + lane] = (_Float16)((a0 + a1) + (a2 + a3));
}

// ---------------- per-(b,t) partial sums over 500 neurons ----------------
__global__ __launch_bounds__(256) void k_S(const _Float16* __restrict__ y,
                                           float* __restrict__ S) {
    const int bt = blockIdx.x;           // 0..255
    const int tid = threadIdx.x;
    const int h = tid & 63, g = tid >> 6;
    const _Float16* base = y + (size_t)bt * (NNEUR * HDIM);
    float acc = 0.f;
    for (int n = g; n < NNEUR; n += 4) acc += (float)base[n * HDIM + h];
    __shared__ float red[256];
    red[tid] = acc;
    __syncthreads();
    if (tid < 64)
        S[bt * 64 + tid] = red[tid] + red[64 + tid] + red[128 + tid] + red[192 + tid];
}

// ---------------- attention MLP + pooling + FC head (one block) ----------------
__global__ __launch_bounds__(256) void k_final(
    const float* __restrict__ S, const float* __restrict__ W1,
    const float* __restrict__ W2, const float* __restrict__ fcW,
    const float* __restrict__ fcb, float* __restrict__ out)
{
    __shared__ float xt[256];
    __shared__ float a1[128];
    __shared__ float attn[256];
    __shared__ float pooled[512];
    const int tid = threadIdx.x;

    {
        float s = 0.f;
        const float* p = S + tid * 64;
#pragma unroll
        for (int hh = 0; hh < 64; ++hh) s += p[hh];
        xt[tid] = s * (1.0f / 32000.0f);
    }
    __syncthreads();
    if (tid < 128) {
        int b = tid >> 4, i = tid & 15;
        float s = 0.f;
#pragma unroll
        for (int t = 0; t < 32; ++t) s += xt[b * 32 + t] * W1[i * 32 + t];
        a1[tid] = fmaxf(s, 0.f);
    }
    __syncthreads();
    {
        int b = tid >> 5, t = tid & 31;
        float s = 0.f;
#pragma unroll
        for (int i = 0; i < 16; ++i) s += a1[b * 16 + i] * W2[t * 16 + i];
        attn[tid] = 1.0f / (1.0f + __expf(-s));
    }
    __syncthreads();
    for (int o = tid; o < 512; o += 256) {
        int b = o >> 6, h = o & 63;
        float s = 0.f;
#pragma unroll
        for (int t = 0; t < 32; ++t) s += attn[b * 32 + t] * S[(b * 32 + t) * 64 + h];
        pooled[o] = s;
    }
    __syncthreads();
    if (tid < BATCHB * NSTEPS) {
        int b = tid / NSTEPS, st = tid % NSTEPS;
        float acc = fcb[st];
#pragma unroll
        for (int h = 0; h < 64; ++h) acc += pooled[b * 64 + h] * fcW[st * 64 + h];
        out[b * NSTEPS + st] = acc;
    }
}

extern "C" void kernel_launch(void* const* d_in, const int* in_sizes, int n_in,
                              void* d_out, int out_size, void* d_ws, size_t ws_size,
                              hipStream_t stream) {
    const float* x   = (const float*)d_in[0];
    const int*   ei  = (const int*)  d_in[1];
    const float* ea  = (const float*)d_in[2];
    // d_in[3] = batch: unused by the reference computation
    const float* Wih = (const float*)d_in[4];
    const float* Whh = (const float*)d_in[5];
    const float* bih = (const float*)d_in[6];
    const float* bhh = (const float*)d_in[7];
    const float* Wg  = (const float*)d_in[8];
    const float* W1  = (const float*)d_in[9];
    const float* W2  = (const float*)d_in[10];
    const float* fcW = (const float*)d_in[11];
    const float* fcb = (const float*)d_in[12];
    float* out = (float*)d_out;

    // workspace layout (~46 MB); y aliases xh (dead after k_recHist)
    char* p = (char*)d_ws;
    unsigned long long* dc = (unsigned long long*)p; p += sizeof(unsigned long long) * NTOT;  // 1.02 MB
    int2*  se  = (int2*)p;         p += sizeof(int2) * ECOUNT;                                // 8.19 MB
    _Float16* xh  = (_Float16*)p;  p += sizeof(_Float16) * (size_t)XELEMS;                    // 16.38 MB
    _Float16* xwh = (_Float16*)p;  p += sizeof(_Float16) * (size_t)NTOT * HDIM;               // 16.38 MB
    float* dis = (float*)p;        p += sizeof(float) * NTOT;                                 // 0.51 MB
    int*   off = (int*)p;          p += sizeof(int) * (NTOT + 2);                             // 0.51 MB
    int*   bsum= (int*)p;          p += sizeof(int) * 512;
    int*   boff= (int*)p;          p += sizeof(int) * 512;
    float* S   = (float*)p;        p += sizeof(float) * 16384;
    unsigned short* rank = (unsigned short*)p;                                                // 2.05 MB
    _Float16* y = xh;   // reuse: xh is consumed only by k_recHist

    k_prep    <<<(XELEMS / 8 + 255) / 256, 256, 0, stream>>>(x, xh, dc);
    k_recHist <<<REC_BLOCKS + HIST_BLOCKS, 256, 0, stream>>>(
        xh, Wih, Whh, bih, bhh, Wg, xwh, ei, ea, dc, rank);
    k_dis     <<<(NTOT + 255) / 256, 256, 0, stream>>>(dc, dis);
    k_scan1   <<<NTOT / 256, 256, 0, stream>>>(dc, bsum);
    k_scan2   <<<1, 512, 0, stream>>>(bsum, boff);
    k_scan3   <<<NTOT / 256, 256, 0, stream>>>(dc, boff, off);
    k_esc     <<<(ECOUNT + 255) / 256, 256, 0, stream>>>(ei, ea, dis, off, rank, se);
    k_gather  <<<NTOT / 4, 256, 0, stream>>>(xwh, off, se, dis, y);
    k_S       <<<256, 256, 0, stream>>>(y, S);
    k_final   <<<1, 256, 0, stream>>>(S, W1, W2, fcW, fcb, out);
}